// Round 6
// baseline (4310.715 us; speedup 1.0000x reference)
//
#include <hip/hip_runtime.h>
#include <cstddef>
#include <cstdint>

#define BB    4096
#define TT    64
#define OBSN  16
#define NSTAT 8
#define LAT   32
#define HID   64
#define NK    8
#define SMP   64      // samples per block (= lanes per wave)
#define NWV   8       // waves per block
#define BLK   (NWV * 64)
#define HSTR  68      // H row stride (dwords); 68%32==4 -> 8-lane groups tile all 32 banks (b128 conflict-free)
#define ZSTR  36      // ZB row stride; 36%32==4 -> same property
#define OSTR  20      // decode staging row stride (16 data + 4 pad, 16B-aligned rows)

// Constant-address-space weight pointers: uniform address -> s_load via scalar
// cache -> weight lands in SGPR, feeds v_fma's single-SGPR operand slot.
// Zero VALU / zero LDS cost per weight. Weights are never written -> AS4 legal.
typedef const __attribute__((address_space(4))) float cfloat;
__device__ __forceinline__ cfloat* cptr(const float* p) {
    return (cfloat*)(uintptr_t)p;
}

__device__ __forceinline__ float fast_tanh(float x) {
    // tanh(x) = 1 - 2/(exp(2x)+1); branchless, exact at +/-inf
    float e = __expf(2.0f * x);
    return 1.0f - 2.0f / (e + 1.0f);
}

// Dense layer j-chunk. act: this lane's LDS activation row (per-lane b128,
// conflict-free stride). Wj/Bj: AS4 scalar-path weights, pre-offset by the
// wave's j-chunk; all further indices compile-time.
template<int NIN, int NOUT, int JCN>
__device__ __forceinline__ void dense_sc(const float* __restrict__ act,
                                         cfloat* __restrict__ Wj,
                                         cfloat* __restrict__ Bj,
                                         float* acc) {
    #pragma unroll
    for (int j = 0; j < JCN; ++j) acc[j] = Bj[j];
    #pragma unroll
    for (int iq = 0; iq < NIN / 4; ++iq) {
        float4 v = *(const float4*)(act + iq * 4);
        #pragma unroll
        for (int di = 0; di < 4; ++di) {
            const float vv = (di == 0) ? v.x : (di == 1) ? v.y : (di == 2) ? v.z : v.w;
            cfloat* wr = Wj + (iq * 4 + di) * NOUT;
            #pragma unroll
            for (int j = 0; j < JCN; ++j) acc[j] = fmaf(vv, wr[j], acc[j]);
        }
    }
}

__global__ __launch_bounds__(BLK, 6) void node_scal(
    const float* __restrict__ tg, const float* __restrict__ xg,
    const float* __restrict__ zg,
    const float* __restrict__ eW1, const float* __restrict__ eb1,
    const float* __restrict__ eW2, const float* __restrict__ eb2,
    const float* __restrict__ eW3, const float* __restrict__ eb3,
    const float* __restrict__ oW1, const float* __restrict__ ob1,
    const float* __restrict__ oW2, const float* __restrict__ ob2,
    const float* __restrict__ oW3, const float* __restrict__ ob3,
    const float* __restrict__ dWg, const float* __restrict__ dbg,
    float* __restrict__ outg)
{
    __shared__ __align__(16) float H0[SMP][HSTR];   // 17.4 KB
    __shared__ __align__(16) float H1[SMP][HSTR];   // 17.4 KB
    __shared__ __align__(16) float ZB[SMP][ZSTR];   //  9.2 KB
    __shared__ __align__(16) float OB[SMP][OSTR];   //  5.1 KB  (total 49 KB -> 3 blocks/CU)

    const int tid  = threadIdx.x;
    const int lane = tid & 63;                                   // sample
    const int wid  = __builtin_amdgcn_readfirstlane((int)(tid >> 6));
    const int k     = blockIdx.x >> 6;                           // 64 blocks / k
    const int sbase = (blockIdx.x & 63) * SMP;
    const int b     = sbase + lane;
    const int j0 = wid * 8;   // 64-wide layers
    const int j3 = wid * 4;   // 32-wide layer
    const int od = wid * 2;   // 16-wide decode

    float* Hrow0 = &H0[lane][0];
    float* Hrow1 = &H1[lane][0];
    float* Zrow  = &ZB[lane][0];

    // Scalar-path weight pointers (all wave-uniform).
    cfloat* W1j = cptr(oW1 + k * (LAT * HID) + j0);
    cfloat* B1j = cptr(ob1 + k * HID + j0);
    cfloat* W2j = cptr(oW2 + k * (HID * HID) + j0);
    cfloat* B2j = cptr(ob2 + k * HID + j0);
    cfloat* W3j = cptr(oW3 + k * (HID * LAT) + j3);
    cfloat* B3j = cptr(ob3 + k * LAT + j3);
    cfloat* WDj = cptr(dWg + od);
    cfloat* BDj = cptr(dbg + od);
    cfloat* tgc = cptr(tg);

    // ---- encoder input: concat(x[b,0,:16], z[b,:8]) -> ZB cols 0..23 ----
    if (wid == 0) {
        const float4* xr = (const float4*)(xg + (size_t)b * (TT * OBSN));
        float4* dst = (float4*)Zrow;
        dst[0] = xr[0]; dst[1] = xr[1]; dst[2] = xr[2]; dst[3] = xr[3];
        const float4* zr = (const float4*)(zg + (size_t)b * NSTAT);
        dst[4] = zr[0]; dst[5] = zr[1];
    }
    __syncthreads();

    float acc[8];
    // encoder L1: 24 -> 64 tanh -> H0
    dense_sc<OBSN + NSTAT, HID, 8>(Zrow, cptr(eW1 + j0), cptr(eb1 + j0), acc);
    {
        float4* o = (float4*)(Hrow0 + j0);
        o[0] = make_float4(fast_tanh(acc[0]), fast_tanh(acc[1]), fast_tanh(acc[2]), fast_tanh(acc[3]));
        o[1] = make_float4(fast_tanh(acc[4]), fast_tanh(acc[5]), fast_tanh(acc[6]), fast_tanh(acc[7]));
    }
    __syncthreads();
    // encoder L2: 64 -> 64 tanh -> H1
    dense_sc<HID, HID, 8>(Hrow0, cptr(eW2 + j0), cptr(eb2 + j0), acc);
    {
        float4* o = (float4*)(Hrow1 + j0);
        o[0] = make_float4(fast_tanh(acc[0]), fast_tanh(acc[1]), fast_tanh(acc[2]), fast_tanh(acc[3]));
        o[1] = make_float4(fast_tanh(acc[4]), fast_tanh(acc[5]), fast_tanh(acc[6]), fast_tanh(acc[7]));
    }
    __syncthreads();
    // encoder L3: 64 -> 32 -> z0
    float zc[4];
    dense_sc<HID, LAT, 4>(Hrow1, cptr(eW3 + j3), cptr(eb3 + j3), zc);
    *(float4*)(Zrow + j3) = make_float4(zc[0], zc[1], zc[2], zc[3]);
    __syncthreads();

    const size_t kb = (size_t)(k * BB + sbase);

    // ---- decode t=0: compute float2/thread -> OB; flush as full 64B lines ----
    {
        float oa[2];
        dense_sc<LAT, OBSN, 2>(Zrow, WDj, BDj, oa);
        *(float2*)(&OB[lane][od]) = make_float2(oa[0], oa[1]);
    }
    __syncthreads();
    if (tid < 256) {
        const int s = tid >> 2, q = tid & 3;
        float4 v = *(const float4*)(&OB[s][q * 4]);
        *(float4*)(outg + (kb + s) * (TT * OBSN) + q * 4) = v;
    }

    // ---- RK4 time loop ----
    float tprev = tgc[0];
    #pragma unroll 1
    for (int step = 1; step < TT; ++step) {
        const float tcur = tgc[step];
        const float h = tcur - tprev;
        tprev = tcur;

        float zn[4];
        #pragma unroll
        for (int p = 0; p < 4; ++p) zn[p] = zc[p];

        #pragma unroll 1
        for (int stage = 0; stage < 4; ++stage) {
            // L1: ZB(32) -> H0(64) tanh
            dense_sc<LAT, HID, 8>(Zrow, W1j, B1j, acc);
            {
                float4* o = (float4*)(Hrow0 + j0);
                o[0] = make_float4(fast_tanh(acc[0]), fast_tanh(acc[1]), fast_tanh(acc[2]), fast_tanh(acc[3]));
                o[1] = make_float4(fast_tanh(acc[4]), fast_tanh(acc[5]), fast_tanh(acc[6]), fast_tanh(acc[7]));
            }
            __syncthreads();                       // B1: H0 visible; ZB reads done
            // L2: H0(64) -> H1(64) tanh
            dense_sc<HID, HID, 8>(Hrow0, W2j, B2j, acc);
            {
                float4* o = (float4*)(Hrow1 + j0);
                o[0] = make_float4(fast_tanh(acc[0]), fast_tanh(acc[1]), fast_tanh(acc[2]), fast_tanh(acc[3]));
                o[1] = make_float4(fast_tanh(acc[4]), fast_tanh(acc[5]), fast_tanh(acc[6]), fast_tanh(acc[7]));
            }
            __syncthreads();                       // B2: H1 visible
            // L3: H1(64) -> f(32) chunk + RK4 combine
            float fo[4];
            dense_sc<HID, LAT, 4>(Hrow1, W3j, B3j, fo);

            const float czn = (stage == 0 || stage == 3) ? h * (1.0f / 6.0f)
                                                         : h * (1.0f / 3.0f);
            #pragma unroll
            for (int p = 0; p < 4; ++p) zn[p] = fmaf(czn, fo[p], zn[p]);

            if (stage < 3) {
                const float czt = (stage == 2) ? h : 0.5f * h;
                float4 zt;
                zt.x = fmaf(czt, fo[0], zc[0]);
                zt.y = fmaf(czt, fo[1], zc[1]);
                zt.z = fmaf(czt, fo[2], zc[2]);
                zt.w = fmaf(czt, fo[3], zc[3]);
                *(float4*)(Zrow + j3) = zt;
            } else {
                #pragma unroll
                for (int p = 0; p < 4; ++p) zc[p] = zn[p];
                *(float4*)(Zrow + j3) = make_float4(zn[0], zn[1], zn[2], zn[3]);
            }
            __syncthreads();                       // B3: z_next visible; H1 reads done
        }

        // decode this step -> OB, then full-line flush
        {
            float oa[2];
            dense_sc<LAT, OBSN, 2>(Zrow, WDj, BDj, oa);
            *(float2*)(&OB[lane][od]) = make_float2(oa[0], oa[1]);
        }
        __syncthreads();                           // B_E: OB complete
        if (tid < 256) {
            const int s = tid >> 2, q = tid & 3;
            float4 v = *(const float4*)(&OB[s][q * 4]);
            *(float4*)(outg + (kb + s) * (TT * OBSN) + (size_t)step * OBSN + q * 4) = v;
        }
        // next OB write is 12 barriers away -> no extra barrier needed here
    }
}

extern "C" void kernel_launch(void* const* d_in, const int* in_sizes, int n_in,
                              void* d_out, int out_size, void* d_ws, size_t ws_size,
                              hipStream_t stream) {
    const float* tg  = (const float*)d_in[0];
    const float* xg  = (const float*)d_in[1];
    const float* zg  = (const float*)d_in[2];
    const float* eW1 = (const float*)d_in[3];
    const float* eb1 = (const float*)d_in[4];
    const float* eW2 = (const float*)d_in[5];
    const float* eb2 = (const float*)d_in[6];
    const float* eW3 = (const float*)d_in[7];
    const float* eb3 = (const float*)d_in[8];
    const float* oW1 = (const float*)d_in[9];
    const float* ob1 = (const float*)d_in[10];
    const float* oW2 = (const float*)d_in[11];
    const float* ob2 = (const float*)d_in[12];
    const float* oW3 = (const float*)d_in[13];
    const float* ob3 = (const float*)d_in[14];
    const float* dW  = (const float*)d_in[15];
    const float* db  = (const float*)d_in[16];
    float* outg = (float*)d_out;

    dim3 grid(NK * (BB / SMP));  // 8 * 64 = 512 blocks, 4096 waves
    node_scal<<<grid, BLK, 0, stream>>>(
        tg, xg, zg, eW1, eb1, eW2, eb2, eW3, eb3,
        oW1, ob1, oW2, ob2, oW3, ob3, dW, db, outg);
}